// Round 3
// baseline (45405.612 us; speedup 1.0000x reference)
//
#include <hip/hip_runtime.h>
#include <hip/hip_bf16.h>
#include <hip/hip_cooperative_groups.h>

namespace cg = cooperative_groups;

#define B_    256
#define S_    512
#define H_    256
#define TLEN_ 32
#define DI_   5
#define ENCSTRIDE 131072   // S_*H_

// ---------------------------------------------------------------------------
// init: zero H ping-pong buffers, set decoder inp0 = ones
// ---------------------------------------------------------------------------
__global__ __launch_bounds__(256) void init_kernel(float* H1, float* H2, float* PRD) {
    int i = blockIdx.x * 256 + threadIdx.x;      // grid 512 -> 131072
    H1[i] = 0.f; H2[i] = 0.f;
    if (i < B_ * DI_) PRD[i] = 1.0f;
}

// ---------------------------------------------------------------------------
// pack a [1024][256] row-major weight into [k4][n] float4 layout
// ---------------------------------------------------------------------------
__global__ __launch_bounds__(256) void pack_kernel(const float* __restrict__ m,
                                                   float4* __restrict__ out) {
    int idx = blockIdx.x * 256 + threadIdx.x;    // grid 256 -> 65536
    int k4 = idx >> 10, n = idx & 1023;
    out[idx] = ((const float4*)m)[n * 64 + k4];
}

// ---------------------------------------------------------------------------
// Weff[n][m] = sum_k wih_d1[n][k]*wdi[k][m]; beff[n] = b_d1[n] + wih_d1[n]·bdi
// ---------------------------------------------------------------------------
__global__ __launch_bounds__(256) void weff_kernel(const float* __restrict__ wih_d1,
                                                   const float* __restrict__ wdi,
                                                   const float* __restrict__ bdi,
                                                   const float* __restrict__ b_d1,
                                                   float* __restrict__ weff,
                                                   float* __restrict__ beff) {
    int n = blockIdx.x * 256 + threadIdx.x;      // grid 4 -> 1024
    float acc[DI_] = {0.f, 0.f, 0.f, 0.f, 0.f};
    float accb = 0.f;
    for (int k = 0; k < H_; k++) {
        float w = wih_d1[n * H_ + k];
        accb += w * bdi[k];
#pragma unroll
        for (int m = 0; m < DI_; m++) acc[m] += w * wdi[k * DI_ + m];
    }
#pragma unroll
    for (int m = 0; m < DI_; m++) weff[n * DI_ + m] = acc[m];
    beff[n] = b_d1[n] + accb;
}

// ---------------------------------------------------------------------------
__device__ __forceinline__ void dot4(const float4 xv, const float4 w0, const float4 w1,
                                     const float4 w2, const float4 w3,
                                     float& a0, float& a1, float& a2, float& a3) {
    a0 += xv.x * w0.x + xv.y * w0.y + xv.z * w0.z + xv.w * w0.w;
    a1 += xv.x * w1.x + xv.y * w1.y + xv.z * w1.z + xv.w * w1.w;
    a2 += xv.x * w2.x + xv.y * w2.y + xv.z * w2.z + xv.w * w2.w;
    a3 += xv.x * w3.x + xv.y * w3.y + xv.z * w3.z + xv.w * w3.w;
}

__device__ __forceinline__ void lstm_epilogue(float a0, float a1, float a2, float a3,
                                              float cold, float& cn, float& hn) {
    float ii = 1.f / (1.f + expf(-a0));
    float ff = 1.f / (1.f + expf(-a1));
    float gg = tanhf(a2);
    float oo = 1.f / (1.f + expf(-a3));
    cn = ff * cold + ii * gg;
    hn = oo * tanhf(cn);
}

// ---------------------------------------------------------------------------
// Persistent encoder. 256 blocks x 512 threads, cooperative.
// threads 0..255: layer-1 step t; threads 256..511: layer-2 step t-1.
// Each block owns fixed (b,j) 16x16 tiles for both layers -> c stays in reg.
// ---------------------------------------------------------------------------
__global__ __launch_bounds__(512) void enc_persist_kernel(
    const float* __restrict__ srcs,
    const float* __restrict__ wih_e1,
    const float4* __restrict__ whh_e1p,
    const float4* __restrict__ wih_e2p,
    const float4* __restrict__ whh_e2p,
    const float* __restrict__ b_e1,
    const float* __restrict__ b_e2,
    float* __restrict__ H1,              // [2][65536] ping-pong
    float* __restrict__ H2,              // [2][65536] ping-pong
    float* __restrict__ C2g,             // final c_enc out
    __hip_bfloat16* __restrict__ encbf)
{
    cg::grid_group grid = cg::this_grid();
    __shared__ float sX1[16][8];
    __shared__ float sH1[16][260];
    __shared__ float sE1[16][260];
    __shared__ float sH2[16][260];

    const int tid = threadIdx.x;
    const int bid = blockIdx.x;
    const int b0 = (bid >> 4) * 16, j0 = (bid & 15) * 16;
    const bool l1 = (tid < 256);
    const int t1 = l1 ? tid : tid - 256;
    const int bl = t1 >> 4, jl = t1 & 15;
    const int b = b0 + bl, j = j0 + jl;
    const int idx = b * H_ + j;

    float creg = 0.f;
    float bb0, bb1, bb2, bb3;
    if (l1) { bb0 = b_e1[j]; bb1 = b_e1[256 + j]; bb2 = b_e1[512 + j]; bb3 = b_e1[768 + j]; }
    else    { bb0 = b_e2[j]; bb1 = b_e2[256 + j]; bb2 = b_e2[512 + j]; bb3 = b_e2[768 + j]; }

    for (int t = 0; t <= S_; ++t) {
        // ---------------- stage into LDS ----------------
        if (l1) {
            if (t < S_) {
                if (t1 < 16 * DI_) {
                    int r = t1 / DI_, c = t1 % DI_;
                    sX1[r][c] = srcs[((long)(b0 + r) * S_ + t) * DI_ + c];
                }
                const float* hp = H1 + (((t & 1) ^ 1) << 16);
                for (int i = t1; i < 1024; i += 256) {
                    int r = i >> 6, c4 = i & 63;
                    ((float4*)&sH1[r][0])[c4] = ((const float4*)(hp + (b0 + r) * H_))[c4];
                }
            }
        } else {
            if (t >= 1) {
                int u = t - 1;
                const float* xp = H1 + ((u & 1) << 16);
                const float* hp = H2 + (((u & 1) ^ 1) << 16);
                for (int i = t1; i < 1024; i += 256) {
                    int r = i >> 6, c4 = i & 63;
                    ((float4*)&sE1[r][0])[c4] = ((const float4*)(xp + (b0 + r) * H_))[c4];
                    ((float4*)&sH2[r][0])[c4] = ((const float4*)(hp + (b0 + r) * H_))[c4];
                }
            }
        }
        __syncthreads();
        // ---------------- compute ----------------
        if (l1) {
            if (t < S_) {
                float a0 = bb0, a1 = bb1, a2 = bb2, a3 = bb3;
#pragma unroll
                for (int k = 0; k < DI_; k++) {
                    float xv = sX1[bl][k];
                    a0 += xv * wih_e1[j * DI_ + k];
                    a1 += xv * wih_e1[(256 + j) * DI_ + k];
                    a2 += xv * wih_e1[(512 + j) * DI_ + k];
                    a3 += xv * wih_e1[(768 + j) * DI_ + k];
                }
#pragma unroll 4
                for (int k4 = 0; k4 < 64; k4++) {
                    float4 xv = ((const float4*)&sH1[bl][0])[k4];
                    dot4(xv, whh_e1p[(k4 << 10) + j], whh_e1p[(k4 << 10) + 256 + j],
                         whh_e1p[(k4 << 10) + 512 + j], whh_e1p[(k4 << 10) + 768 + j],
                         a0, a1, a2, a3);
                }
                float cn, hn;
                lstm_epilogue(a0, a1, a2, a3, creg, cn, hn);
                creg = cn;
                H1[((t & 1) << 16) + idx] = hn;
            }
        } else {
            if (t >= 1) {
                int u = t - 1;
                float a0 = bb0, a1 = bb1, a2 = bb2, a3 = bb3;
#pragma unroll 4
                for (int k4 = 0; k4 < 64; k4++) {
                    float4 xv = ((const float4*)&sE1[bl][0])[k4];
                    dot4(xv, wih_e2p[(k4 << 10) + j], wih_e2p[(k4 << 10) + 256 + j],
                         wih_e2p[(k4 << 10) + 512 + j], wih_e2p[(k4 << 10) + 768 + j],
                         a0, a1, a2, a3);
                }
#pragma unroll 4
                for (int k4 = 0; k4 < 64; k4++) {
                    float4 xv = ((const float4*)&sH2[bl][0])[k4];
                    dot4(xv, whh_e2p[(k4 << 10) + j], whh_e2p[(k4 << 10) + 256 + j],
                         whh_e2p[(k4 << 10) + 512 + j], whh_e2p[(k4 << 10) + 768 + j],
                         a0, a1, a2, a3);
                }
                float cn, hn;
                lstm_epilogue(a0, a1, a2, a3, creg, cn, hn);
                creg = cn;
                H2[((u & 1) << 16) + idx] = hn;
                encbf[(long)b * ENCSTRIDE + u * H_ + j] = __float2bfloat16(hn);
                if (u == S_ - 1) C2g[idx] = creg;
            }
        }
        grid.sync();
    }
}

// ---------------------------------------------------------------------------
// Persistent decoder. 256 blocks x 256 threads, cooperative. 32 steps x
// 6 stages with grid.sync() between. c2 carried in registers.
// ---------------------------------------------------------------------------
__global__ __launch_bounds__(256) void dec_persist_kernel(
    const float* __restrict__ weff,        // [1024][5]
    const float4* __restrict__ whh_d1p,
    const float4* __restrict__ wih_d2p,
    const float* __restrict__ beff,
    const float* __restrict__ b_d2,
    float* __restrict__ H2F,               // carry h (init = h_enc)
    const float* __restrict__ C2g,         // c_enc initial
    float* __restrict__ H1D,
    float* __restrict__ EN,
    float* __restrict__ WSM,
    float* __restrict__ CTX,
    float* __restrict__ PRD,
    const __hip_bfloat16* __restrict__ encbf,
    const float* __restrict__ ww, const float* __restrict__ bw,
    const float* __restrict__ wop, const float* __restrict__ bop,
    float* __restrict__ OUT0, float* __restrict__ OUT1)
{
    cg::grid_group grid = cg::this_grid();
    __shared__ float sA[16][260];
    __shared__ float sB[16][260];

    const int tid = threadIdx.x;
    const int bid = blockIdx.x;
    const int b0 = (bid >> 4) * 16, j0 = (bid & 15) * 16;
    const int bl = tid >> 4, jl = tid & 15;
    const int cb = b0 + bl, cj = j0 + jl;
    const int idx = cb * H_ + cj;

    float c2reg = C2g[idx];
    const float be0 = beff[cj], be1 = beff[256 + cj], be2 = beff[512 + cj], be3 = beff[768 + cj];
    const float bd0 = b_d2[cj], bd1 = b_d2[256 + cj], bd2v = b_d2[512 + cj], bd3 = b_d2[768 + cj];

    for (int t = 0; t < TLEN_; ++t) {
        // ---- cell1: x = PRD (K=5 via weff), h = H2F, c = c2reg -> H1D ----
        if (tid < 16 * DI_) {
            int r = tid / DI_, c = tid % DI_;
            sA[r][c] = PRD[(b0 + r) * DI_ + c];
        }
        for (int i = tid; i < 1024; i += 256) {
            int r = i >> 6, c4 = i & 63;
            ((float4*)&sB[r][0])[c4] = ((const float4*)(H2F + (b0 + r) * H_))[c4];
        }
        __syncthreads();
        {
            float a0 = be0, a1 = be1, a2 = be2, a3 = be3;
#pragma unroll
            for (int k = 0; k < DI_; k++) {
                float xv = sA[bl][k];
                a0 += xv * weff[cj * DI_ + k];
                a1 += xv * weff[(256 + cj) * DI_ + k];
                a2 += xv * weff[(512 + cj) * DI_ + k];
                a3 += xv * weff[(768 + cj) * DI_ + k];
            }
#pragma unroll 4
            for (int k4 = 0; k4 < 64; k4++) {
                float4 xv = ((const float4*)&sB[bl][0])[k4];
                dot4(xv, whh_d1p[(k4 << 10) + cj], whh_d1p[(k4 << 10) + 256 + cj],
                     whh_d1p[(k4 << 10) + 512 + cj], whh_d1p[(k4 << 10) + 768 + cj],
                     a0, a1, a2, a3);
            }
            float cn, hn;
            lstm_epilogue(a0, a1, a2, a3, c2reg, cn, hn);
            H1D[idx] = hn;                 // c1 discarded
        }
        grid.sync();

        // ---- cell2: x = H1D (K=256), h = c = 0 -> H2F, c2reg ----
        for (int i = tid; i < 1024; i += 256) {
            int r = i >> 6, c4 = i & 63;
            ((float4*)&sA[r][0])[c4] = ((const float4*)(H1D + (b0 + r) * H_))[c4];
        }
        __syncthreads();
        {
            float a0 = bd0, a1 = bd1, a2 = bd2v, a3 = bd3;
#pragma unroll 4
            for (int k4 = 0; k4 < 64; k4++) {
                float4 xv = ((const float4*)&sA[bl][0])[k4];
                dot4(xv, wih_d2p[(k4 << 10) + cj], wih_d2p[(k4 << 10) + 256 + cj],
                     wih_d2p[(k4 << 10) + 512 + cj], wih_d2p[(k4 << 10) + 768 + cj],
                     a0, a1, a2, a3);
            }
            float cn, hn;
            lstm_epilogue(a0, a1, a2, a3, 0.f, cn, hn);
            c2reg = cn;
            H2F[idx] = hn;
        }
        grid.sync();

        // ---- energies: block b = bid; E[s][b] = h2[b]·enc[b,s,:] ----
        {
            float* lh = &sA[0][0];
            lh[tid] = H2F[bid * H_ + tid];
            __syncthreads();
            int w = tid >> 6, lane = tid & 63;
            float4 hv = ((const float4*)lh)[lane];
            for (int s = w; s < S_; s += 4) {
                ushort4 uv = ((const ushort4*)(encbf + (long)bid * ENCSTRIDE + s * H_))[lane];
                float p = hv.x * __uint_as_float((unsigned)uv.x << 16)
                        + hv.y * __uint_as_float((unsigned)uv.y << 16)
                        + hv.z * __uint_as_float((unsigned)uv.z << 16)
                        + hv.w * __uint_as_float((unsigned)uv.w << 16);
#pragma unroll
                for (int off = 32; off > 0; off >>= 1) p += __shfl_down(p, off);
                if (lane == 0) EN[s * B_ + bid] = p;
            }
            __syncthreads();
        }
        grid.sync();

        // ---- softmax over b for s = bid, bid+256 ----
        {
            float* red = &sB[0][0];
#pragma unroll
            for (int rr = 0; rr < 2; rr++) {
                int s = bid + rr * 256;
                float v = EN[s * B_ + tid];
                float m = v;
#pragma unroll
                for (int off = 32; off > 0; off >>= 1) m = fmaxf(m, __shfl_down(m, off));
                if ((tid & 63) == 0) red[tid >> 6] = m;
                __syncthreads();
                m = fmaxf(fmaxf(red[0], red[1]), fmaxf(red[2], red[3]));
                __syncthreads();
                float e = expf(v - m);
                float p = e;
#pragma unroll
                for (int off = 32; off > 0; off >>= 1) p += __shfl_down(p, off);
                if ((tid & 63) == 0) red[tid >> 6] = p;
                __syncthreads();
                float sum = red[0] + red[1] + red[2] + red[3];
                WSM[s * B_ + tid] = e / sum;
                __syncthreads();
            }
        }
        grid.sync();

        // ---- context: block b = bid ----
        {
            float* lw = &sA[0][0];   // 512 floats
            lw[tid] = WSM[tid * B_ + bid];
            lw[256 + tid] = WSM[(256 + tid) * B_ + bid];
            __syncthreads();
            float acc = 0.f;
            const __hip_bfloat16* ep = encbf + (long)bid * ENCSTRIDE + tid;
#pragma unroll 8
            for (int s = 0; s < S_; s++) acc += lw[s] * __bfloat162float(ep[s * H_]);
            OUT1[(long)bid * (TLEN_ * H_) + t * H_ + tid] = acc;
            CTX[bid * H_ + tid] = acc;
            __syncthreads();
        }
        grid.sync();

        // ---- decout: block b = bid (wave 0 active) ----
        if (tid < 64) {
            float a[DI_] = {0.f, 0.f, 0.f, 0.f, 0.f};
            for (int k = tid; k < 2 * H_; k += 64) {
                float v = (k < H_) ? H2F[bid * H_ + k] : CTX[bid * H_ + k - H_];
#pragma unroll
                for (int m = 0; m < DI_; m++) a[m] += v * ww[m * (2 * H_) + k];
            }
#pragma unroll
            for (int m = 0; m < DI_; m++)
                for (int off = 32; off > 0; off >>= 1) a[m] += __shfl_down(a[m], off);
            if (tid == 0) {
                float t5[DI_];
#pragma unroll
                for (int m = 0; m < DI_; m++) t5[m] = tanhf(a[m] + bw[m]);
#pragma unroll
                for (int m2 = 0; m2 < DI_; m2++) {
                    float o = bop[m2];
#pragma unroll
                    for (int m = 0; m < DI_; m++) o += t5[m] * wop[m2 * DI_ + m];
                    OUT0[(long)bid * (TLEN_ * DI_) + t * DI_ + m2] = o;
                    PRD[bid * DI_ + m2] = o;
                }
            }
        }
        grid.sync();
    }
}

// ---------------------------------------------------------------------------
extern "C" void kernel_launch(void* const* d_in, const int* in_sizes, int n_in,
                              void* d_out, int out_size, void* d_ws, size_t ws_size,
                              hipStream_t stream) {
    const float* srcs   = (const float*)d_in[0];
    const float* wih_e1 = (const float*)d_in[1];
    const float* whh_e1 = (const float*)d_in[2];
    const float* b_e1   = (const float*)d_in[3];
    const float* wih_e2 = (const float*)d_in[4];
    const float* whh_e2 = (const float*)d_in[5];
    const float* b_e2   = (const float*)d_in[6];
    const float* wdi    = (const float*)d_in[7];
    const float* bdi    = (const float*)d_in[8];
    const float* wih_d1 = (const float*)d_in[9];
    const float* whh_d1 = (const float*)d_in[10];
    const float* b_d1   = (const float*)d_in[11];
    const float* wih_d2 = (const float*)d_in[12];
    const float* whh_d2 = (const float*)d_in[13];   // unused (h=0 in cell2)
    const float* b_d2   = (const float*)d_in[14];
    const float* ww     = (const float*)d_in[15];
    const float* bw     = (const float*)d_in[16];
    const float* wop    = (const float*)d_in[17];
    const float* bop    = (const float*)d_in[18];
    (void)whh_d2;

    float* ws = (float*)d_ws;
    __hip_bfloat16* ENCBF = (__hip_bfloat16*)d_ws;   // 33.5M bf16 = 16,777,216 float slots
    size_t o = 16777216;
    float4* PKE1 = (float4*)(ws + o); o += 262144;   // whh_e1 packed
    float4* PKX2 = (float4*)(ws + o); o += 262144;   // wih_e2 packed
    float4* PKH2 = (float4*)(ws + o); o += 262144;   // whh_e2 packed
    float4* PKD1 = (float4*)(ws + o); o += 262144;   // whh_d1 packed
    float4* PKD2 = (float4*)(ws + o); o += 262144;   // wih_d2 packed
    float* H1  = ws + o; o += 131072;                // [2][65536]
    float* H2  = ws + o; o += 131072;                // [2][65536]
    float* C2  = ws + o; o += 65536;
    float* H1D = ws + o; o += 65536;
    float* EN  = ws + o; o += 131072;
    float* WSM = ws + o; o += 131072;
    float* CTX = ws + o; o += 65536;
    float* PRD = ws + o; o += 1280;
    float* WEF = ws + o; o += 5120;
    float* BEF = ws + o; o += 1024;

    float* OUT0 = (float*)d_out;
    float* OUT1 = OUT0 + (size_t)B_ * TLEN_ * DI_;

    dim3 t256(256);

    init_kernel<<<dim3(512), t256, 0, stream>>>(H1, H2, PRD);
    pack_kernel<<<dim3(256), t256, 0, stream>>>(whh_e1, PKE1);
    pack_kernel<<<dim3(256), t256, 0, stream>>>(wih_e2, PKX2);
    pack_kernel<<<dim3(256), t256, 0, stream>>>(whh_e2, PKH2);
    pack_kernel<<<dim3(256), t256, 0, stream>>>(whh_d1, PKD1);
    pack_kernel<<<dim3(256), t256, 0, stream>>>(wih_d2, PKD2);
    weff_kernel<<<dim3(4), t256, 0, stream>>>(wih_d1, wdi, bdi, b_d1, WEF, BEF);

    // ---------------- encoder: one persistent cooperative kernel ----------------
    {
        void* args[] = {
            (void*)&srcs, (void*)&wih_e1, (void*)&PKE1, (void*)&PKX2, (void*)&PKH2,
            (void*)&b_e1, (void*)&b_e2, (void*)&H1, (void*)&H2, (void*)&C2, (void*)&ENCBF
        };
        hipLaunchCooperativeKernel((void*)enc_persist_kernel, dim3(256), dim3(512),
                                   args, 0, stream);
    }

    // h_enc = H2 slot 1 (t=511 odd)
    float* H2F = H2 + 65536;

    // ---------------- decoder: one persistent cooperative kernel ----------------
    {
        void* args[] = {
            (void*)&WEF, (void*)&PKD1, (void*)&PKD2, (void*)&BEF, (void*)&b_d2,
            (void*)&H2F, (void*)&C2, (void*)&H1D, (void*)&EN, (void*)&WSM,
            (void*)&CTX, (void*)&PRD, (void*)&ENCBF,
            (void*)&ww, (void*)&bw, (void*)&wop, (void*)&bop,
            (void*)&OUT0, (void*)&OUT1
        };
        hipLaunchCooperativeKernel((void*)dec_persist_kernel, dim3(256), dim3(256),
                                   args, 0, stream);
    }
}

// Round 6
// 32877.487 us; speedup vs baseline: 1.3811x; 1.3811x over previous
//
#include <hip/hip_runtime.h>
#include <hip/hip_bf16.h>
#include <hip/hip_cooperative_groups.h>

namespace cg = cooperative_groups;

#define B_    256
#define S_    512
#define H_    256
#define TLEN_ 32
#define DI_   5
#define ENCSTRIDE 131072   // S_*H_

// ---------------------------------------------------------------------------
// init: zero h ping-pong buffers, set decoder inp0 = ones
// ---------------------------------------------------------------------------
__global__ __launch_bounds__(256) void init_kernel(float* HX1, float* HX2, float* PRD) {
    int i = blockIdx.x * 256 + threadIdx.x;      // grid 512 -> 131072
    HX1[i] = 0.f; HX2[i] = 0.f;
    if (i < B_ * DI_) PRD[i] = 1.0f;
}

// ---------------------------------------------------------------------------
// pack a [1024][256] row-major weight into [k4][n] float4 layout (decoder)
// ---------------------------------------------------------------------------
__global__ __launch_bounds__(256) void pack_kernel(const float* __restrict__ m,
                                                   float4* __restrict__ out) {
    int idx = blockIdx.x * 256 + threadIdx.x;    // grid 256 -> 65536
    int k4 = idx >> 10, n = idx & 1023;
    out[idx] = ((const float4*)m)[n * 64 + k4];
}

// ---------------------------------------------------------------------------
// Weff[n][m] = sum_k wih_d1[n][k]*wdi[k][m]; beff[n] = b_d1[n] + wih_d1[n]·bdi
// ---------------------------------------------------------------------------
__global__ __launch_bounds__(256) void weff_kernel(const float* __restrict__ wih_d1,
                                                   const float* __restrict__ wdi,
                                                   const float* __restrict__ bdi,
                                                   const float* __restrict__ b_d1,
                                                   float* __restrict__ weff,
                                                   float* __restrict__ beff) {
    int n = blockIdx.x * 256 + threadIdx.x;      // grid 4 -> 1024
    float acc[DI_] = {0.f, 0.f, 0.f, 0.f, 0.f};
    float accb = 0.f;
    for (int k = 0; k < H_; k++) {
        float w = wih_d1[n * H_ + k];
        accb += w * bdi[k];
#pragma unroll
        for (int m = 0; m < DI_; m++) acc[m] += w * wdi[k * DI_ + m];
    }
#pragma unroll
    for (int m = 0; m < DI_; m++) weff[n * DI_ + m] = acc[m];
    beff[n] = b_d1[n] + accb;
}

// ---------------------------------------------------------------------------
__device__ __forceinline__ void dot4(const float4 xv, const float4 w0, const float4 w1,
                                     const float4 w2, const float4 w3,
                                     float& a0, float& a1, float& a2, float& a3) {
    a0 += xv.x * w0.x + xv.y * w0.y + xv.z * w0.z + xv.w * w0.w;
    a1 += xv.x * w1.x + xv.y * w1.y + xv.z * w1.z + xv.w * w1.w;
    a2 += xv.x * w2.x + xv.y * w2.y + xv.z * w2.z + xv.w * w2.w;
    a3 += xv.x * w3.x + xv.y * w3.y + xv.z * w3.z + xv.w * w3.w;
}

__device__ __forceinline__ void lstm_epilogue(float a0, float a1, float a2, float a3,
                                              float cold, float& cn, float& hn) {
    float ii = 1.f / (1.f + expf(-a0));
    float ff = 1.f / (1.f + expf(-a1));
    float gg = tanhf(a2);
    float oo = 1.f / (1.f + expf(-a3));
    cn = ff * cold + ii * gg;
    hn = oo * tanhf(cn);
}

// ---------------------------------------------------------------------------
// Persistent encoder v3. 256 blocks x 512 threads (1 block/CU), cooperative.
// Block (bt = bid>>5, ct = bid&31): batch rows [bt*32, +32), cols [ct*8, +8).
// Threads 0..255: layer-1 cells (bl = t2>>3, jl = t2&7), step t.
// Threads 256..511: layer-2 cells, step u = t-1 (software pipeline).
// Weight slices LDS-resident (loaded once): whh_e1 / wih_e2 / whh_e2,
// layout wl[k4*32 + g*8 + jl] = row (g*256 + j0 + jl), k-quad k4.
// h1_{t-1} tile staged in LDS (serves layer-1 whh AND layer-2 wih inputs);
// h2_{u-1} rows read directly from global (L2). Per-thread math is exactly
// R3's sequential dot4 over k4 = 0..63 (same FP summation order).
// ---------------------------------------------------------------------------
extern __shared__ char dynlds[];
__global__ __launch_bounds__(512, 1) void enc_persist3(
    const float* __restrict__ srcs,
    const float* __restrict__ wih_e1, const float* __restrict__ whh_e1,
    const float* __restrict__ wih_e2, const float* __restrict__ whh_e2,
    const float* __restrict__ b_e1, const float* __restrict__ b_e2,
    float* __restrict__ HX1, float* __restrict__ HX2,
    float* __restrict__ C2g, float* __restrict__ H2F,
    __hip_bfloat16* __restrict__ encbf)
{
    cg::grid_group grid = cg::this_grid();
    float4* wl1  = (float4*)dynlds;       // [64 k4][32] whh_e1 slice
    float4* wl2x = wl1 + 2048;            // wih_e2 slice
    float4* wl2h = wl2x + 2048;           // whh_e2 slice
    float4* sH1  = wl2h + 2048;           // [32 r][65] staged h1 tile

    const int tid = threadIdx.x, bid = blockIdx.x;
    const int b0 = (bid >> 5) * 32, j0 = (bid & 31) * 8;
    const int half = tid >> 8, t2 = tid & 255;
    const int bl = t2 >> 3, jl = t2 & 7;
    const int b = b0 + bl, j = j0 + jl;
    const int idx = b * H_ + j;

    // ---- load weight slices into LDS (once) ----
    for (int i = tid; i < 2048; i += 512) {
        int k4 = i >> 5, lgc = i & 31;           // lgc = g*8 + jj
        int g = lgc >> 3, jj = lgc & 7;
        int row = g * 256 + j0 + jj;
        wl1[i]  = ((const float4*)(whh_e1 + row * 256))[k4];
        wl2x[i] = ((const float4*)(wih_e2 + row * 256))[k4];
        wl2h[i] = ((const float4*)(whh_e2 + row * 256))[k4];
    }
    // ---- per-thread constants ----
    float bb[4], w1x[4][5];
    if (half == 0) {
#pragma unroll
        for (int g = 0; g < 4; g++) {
            bb[g] = b_e1[g * 256 + j];
#pragma unroll
            for (int k = 0; k < 5; k++) w1x[g][k] = wih_e1[(g * 256 + j) * 5 + k];
        }
    } else {
#pragma unroll
        for (int g = 0; g < 4; g++) bb[g] = b_e2[g * 256 + j];
    }
    float creg = 0.f;

    for (int t = 0; t <= S_; ++t) {
        // ---- stage h1_{t-1} (slot (t&1)^1), rows b0..b0+32, into sH1 ----
        {
            const float* hp = HX1 + (((t & 1) ^ 1) << 16);
            for (int i = tid; i < 2048; i += 512) {
                int r = i >> 6, c4 = i & 63;
                sH1[r * 65 + c4] = ((const float4*)(hp + (b0 + r) * 256))[c4];
            }
        }
        __syncthreads();

        if (half == 0) {
            // ================= layer 1, step t =================
            if (t < S_) {
                float a0 = bb[0], a1 = bb[1], a2 = bb[2], a3 = bb[3];
                const float* xp = srcs + ((long)b * S_ + t) * DI_;
#pragma unroll
                for (int k = 0; k < 5; k++) {
                    float xv = xp[k];
                    a0 += xv * w1x[0][k]; a1 += xv * w1x[1][k];
                    a2 += xv * w1x[2][k]; a3 += xv * w1x[3][k];
                }
#pragma unroll 4
                for (int k4 = 0; k4 < 64; k4++) {
                    float4 hv = sH1[bl * 65 + k4];
                    const float4* wp = wl1 + k4 * 32;
                    dot4(hv, wp[jl], wp[8 + jl], wp[16 + jl], wp[24 + jl],
                         a0, a1, a2, a3);
                }
                float cn, hn;
                lstm_epilogue(a0, a1, a2, a3, creg, cn, hn);
                creg = cn;
                HX1[((t & 1) << 16) + idx] = hn;
            }
        } else {
            // ================= layer 2, step u = t-1 =================
            if (t >= 1) {
                int u = t - 1;
                float a0 = bb[0], a1 = bb[1], a2 = bb[2], a3 = bb[3];
                // wih_e2 · h1_u  (sH1 holds h1_{t-1} = h1_u)
#pragma unroll 4
                for (int k4 = 0; k4 < 64; k4++) {
                    float4 hv = sH1[bl * 65 + k4];
                    const float4* wp = wl2x + k4 * 32;
                    dot4(hv, wp[jl], wp[8 + jl], wp[16 + jl], wp[24 + jl],
                         a0, a1, a2, a3);
                }
                // whh_e2 · h2_{u-1}  (global, slot (u-1)&1 = t&1)
                const float4* h2p = (const float4*)(HX2 + ((t & 1) << 16) + b * 256);
#pragma unroll 4
                for (int k4 = 0; k4 < 64; k4++) {
                    float4 hv = h2p[k4];
                    const float4* wp = wl2h + k4 * 32;
                    dot4(hv, wp[jl], wp[8 + jl], wp[16 + jl], wp[24 + jl],
                         a0, a1, a2, a3);
                }
                float cn, hn;
                lstm_epilogue(a0, a1, a2, a3, creg, cn, hn);
                creg = cn;
                HX2[((u & 1) << 16) + idx] = hn;
                encbf[(long)b * ENCSTRIDE + u * 256 + j] = __float2bfloat16(hn);
                if (u == S_ - 1) { C2g[idx] = creg; H2F[idx] = hn; }
            }
        }
        grid.sync();
    }
}

// ---------------------------------------------------------------------------
// Persistent decoder. 256 blocks x 256 threads, cooperative (grid.sync).
// Cell weights LDS-resident (block's 16-col slice). 5 syncs per step.
// Math identical to R3's passing decoder.
// ---------------------------------------------------------------------------
__global__ __launch_bounds__(256, 1) void dec_persist2(
    const float* __restrict__ weff,
    const float4* __restrict__ PKD1, const float4* __restrict__ PKD2,
    const float* __restrict__ beff, const float* __restrict__ b_d2,
    float* __restrict__ H2F, const float* __restrict__ C2g,
    float* __restrict__ H1D, float* __restrict__ EN, float* __restrict__ WSM,
    float* __restrict__ PRD, const __hip_bfloat16* __restrict__ encbf,
    const float* __restrict__ ww, const float* __restrict__ bw,
    const float* __restrict__ wop, const float* __restrict__ bop,
    float* __restrict__ OUT0, float* __restrict__ OUT1)
{
    cg::grid_group grid = cg::this_grid();
    float4* dwl1 = (float4*)dynlds;          // [64 k4][65 lgc] whh_d1 slice
    float4* dwl2 = dwl1 + 64 * 65;           // wih_d2 slice
    float*  sA   = (float*)(dwl2 + 64 * 65); // [16][260] stage / lh / lw / ctx
    __shared__ float sX[16][5];
    __shared__ float red[4];

    const int tid = threadIdx.x, bid = blockIdx.x;
    const int b0 = (bid >> 4) * 16, j0 = (bid & 15) * 16;
    const int bl = tid >> 4, jl = tid & 15;
    const int cb = b0 + bl, cj = j0 + jl;
    const int idx = cb * H_ + cj;

    for (int i = tid; i < 4096; i += 256) {
        int k4 = i >> 6, lgc = i & 63;
        int gg = lgc >> 4, jj = lgc & 15;
        dwl1[k4 * 65 + lgc] = PKD1[(k4 << 10) + gg * 256 + j0 + jj];
        dwl2[k4 * 65 + lgc] = PKD2[(k4 << 10) + gg * 256 + j0 + jj];
    }

    float c2reg = C2g[idx];
    const float be0 = beff[cj], be1 = beff[256 + cj], be2v = beff[512 + cj], be3 = beff[768 + cj];
    const float bd0 = b_d2[cj], bd1 = b_d2[256 + cj], bd2v = b_d2[512 + cj], bd3 = b_d2[768 + cj];
    float wef[4][5];
#pragma unroll
    for (int g4 = 0; g4 < 4; g4++)
#pragma unroll
        for (int k = 0; k < 5; k++) wef[g4][k] = weff[(g4 * 256 + cj) * 5 + k];

    for (int t = 0; t < TLEN_; ++t) {
        // ---- cell1: x = PRD (K=5 via weff), h = H2F, c = c2reg -> H1D ----
        if (tid < 80) sX[tid / 5][tid % 5] = PRD[b0 * DI_ + tid];
        for (int i = tid; i < 1024; i += 256) {
            int r = i >> 6, c4 = i & 63;
            ((float4*)sA)[r * 65 + c4] = ((const float4*)(H2F + (b0 + r) * H_))[c4];
        }
        __syncthreads();
        {
            float a0 = be0, a1 = be1, a2 = be2v, a3 = be3;
#pragma unroll
            for (int k = 0; k < 5; k++) {
                float xv = sX[bl][k];
                a0 += xv * wef[0][k]; a1 += xv * wef[1][k];
                a2 += xv * wef[2][k]; a3 += xv * wef[3][k];
            }
#pragma unroll 4
            for (int k4 = 0; k4 < 64; k4++) {
                float4 xv = ((const float4*)sA)[bl * 65 + k4];
                const float4* wp = dwl1 + k4 * 65;
                dot4(xv, wp[jl], wp[16 + jl], wp[32 + jl], wp[48 + jl], a0, a1, a2, a3);
            }
            float cn, hn;
            lstm_epilogue(a0, a1, a2, a3, c2reg, cn, hn);
            H1D[idx] = hn;   // c1 discarded
        }
        grid.sync();

        // ---- cell2: x = H1D (K=256), h = c = 0 -> H2F, c2reg ----
        for (int i = tid; i < 1024; i += 256) {
            int r = i >> 6, c4 = i & 63;
            ((float4*)sA)[r * 65 + c4] = ((const float4*)(H1D + (b0 + r) * H_))[c4];
        }
        __syncthreads();
        {
            float a0 = bd0, a1 = bd1, a2 = bd2v, a3 = bd3;
#pragma unroll 4
            for (int k4 = 0; k4 < 64; k4++) {
                float4 xv = ((const float4*)sA)[bl * 65 + k4];
                const float4* wp = dwl2 + k4 * 65;
                dot4(xv, wp[jl], wp[16 + jl], wp[32 + jl], wp[48 + jl], a0, a1, a2, a3);
            }
            float cn, hn;
            lstm_epilogue(a0, a1, a2, a3, 0.f, cn, hn);
            c2reg = cn;
            H2F[idx] = hn;
        }
        grid.sync();

        // ---- energies: block b = bid ----
        {
            float* lh = sA;
            lh[tid] = H2F[bid * H_ + tid];
            __syncthreads();
            int w = tid >> 6, lane = tid & 63;
            float4 hv = ((const float4*)lh)[lane];
            for (int s = w; s < S_; s += 4) {
                ushort4 uv = ((const ushort4*)(encbf + (long)bid * ENCSTRIDE + s * H_))[lane];
                float p = hv.x * __uint_as_float((unsigned)uv.x << 16)
                        + hv.y * __uint_as_float((unsigned)uv.y << 16)
                        + hv.z * __uint_as_float((unsigned)uv.z << 16)
                        + hv.w * __uint_as_float((unsigned)uv.w << 16);
#pragma unroll
                for (int off = 32; off > 0; off >>= 1) p += __shfl_down(p, off);
                if (lane == 0) EN[s * B_ + bid] = p;
            }
            __syncthreads();
        }
        grid.sync();

        // ---- softmax over b for s = bid, bid+256 ----
        {
#pragma unroll
            for (int rr = 0; rr < 2; rr++) {
                int s = bid + rr * 256;
                float v = EN[s * B_ + tid];
                float m = v;
#pragma unroll
                for (int off = 32; off > 0; off >>= 1) m = fmaxf(m, __shfl_down(m, off));
                if ((tid & 63) == 0) red[tid >> 6] = m;
                __syncthreads();
                m = fmaxf(fmaxf(red[0], red[1]), fmaxf(red[2], red[3]));
                __syncthreads();
                float e = expf(v - m);
                float p = e;
#pragma unroll
                for (int off = 32; off > 0; off >>= 1) p += __shfl_down(p, off);
                if ((tid & 63) == 0) red[tid >> 6] = p;
                __syncthreads();
                float sum = red[0] + red[1] + red[2] + red[3];
                WSM[s * B_ + tid] = e / sum;
                __syncthreads();
            }
        }
        grid.sync();

        // ---- context + decout: block b = bid ----
        {
            float* lw = sA;           // 512 floats
            float* ctxb = sA + 1024;  // 256 floats
            lw[tid] = WSM[tid * B_ + bid];
            lw[256 + tid] = WSM[(256 + tid) * B_ + bid];
            __syncthreads();
            float acc = 0.f;
            const __hip_bfloat16* ep = encbf + (long)bid * ENCSTRIDE + tid;
#pragma unroll 8
            for (int s = 0; s < S_; s++) acc += lw[s] * __bfloat162float(ep[s * H_]);
            OUT1[(long)bid * (TLEN_ * H_) + t * H_ + tid] = acc;
            ctxb[tid] = acc;
            __syncthreads();
            if (tid < 64) {
                float a[DI_] = {0.f, 0.f, 0.f, 0.f, 0.f};
                for (int k = tid; k < 2 * H_; k += 64) {
                    float v = (k < H_) ? H2F[bid * H_ + k] : ctxb[k - H_];
#pragma unroll
                    for (int m = 0; m < DI_; m++) a[m] += v * ww[m * (2 * H_) + k];
                }
#pragma unroll
                for (int m = 0; m < DI_; m++)
                    for (int off = 32; off > 0; off >>= 1) a[m] += __shfl_down(a[m], off);
                if (tid == 0) {
                    float t5[DI_];
#pragma unroll
                    for (int m = 0; m < DI_; m++) t5[m] = tanhf(a[m] + bw[m]);
#pragma unroll
                    for (int m2 = 0; m2 < DI_; m2++) {
                        float o = bop[m2];
#pragma unroll
                        for (int m = 0; m < DI_; m++) o += t5[m] * wop[m2 * DI_ + m];
                        OUT0[(long)bid * (TLEN_ * DI_) + t * DI_ + m2] = o;
                        PRD[bid * DI_ + m2] = o;
                    }
                }
            }
        }
        grid.sync();
    }
}

// ---------------------------------------------------------------------------
extern "C" void kernel_launch(void* const* d_in, const int* in_sizes, int n_in,
                              void* d_out, int out_size, void* d_ws, size_t ws_size,
                              hipStream_t stream) {
    const float* srcs   = (const float*)d_in[0];
    const float* wih_e1 = (const float*)d_in[1];
    const float* whh_e1 = (const float*)d_in[2];
    const float* b_e1   = (const float*)d_in[3];
    const float* wih_e2 = (const float*)d_in[4];
    const float* whh_e2 = (const float*)d_in[5];
    const float* b_e2   = (const float*)d_in[6];
    const float* wdi    = (const float*)d_in[7];
    const float* bdi    = (const float*)d_in[8];
    const float* wih_d1 = (const float*)d_in[9];
    const float* whh_d1 = (const float*)d_in[10];
    const float* b_d1   = (const float*)d_in[11];
    const float* wih_d2 = (const float*)d_in[12];
    const float* whh_d2 = (const float*)d_in[13];   // unused (h=0 in cell2)
    const float* b_d2   = (const float*)d_in[14];
    const float* ww     = (const float*)d_in[15];
    const float* bw     = (const float*)d_in[16];
    const float* wop    = (const float*)d_in[17];
    const float* bop    = (const float*)d_in[18];
    (void)whh_d2;

    float* ws = (float*)d_ws;
    __hip_bfloat16* ENCBF = (__hip_bfloat16*)d_ws;   // 33.5M bf16 = 16,777,216 float slots
    size_t o = 16777216;
    float4* PKD1 = (float4*)(ws + o); o += 262144;   // whh_d1 packed
    float4* PKD2 = (float4*)(ws + o); o += 262144;   // wih_d2 packed
    float* HX1 = ws + o; o += 131072;                // [2][65536]
    float* HX2 = ws + o; o += 131072;                // [2][65536]
    float* C2g = ws + o; o += 65536;
    float* H2F = ws + o; o += 65536;
    float* H1D = ws + o; o += 65536;
    float* EN  = ws + o; o += 131072;
    float* WSM = ws + o; o += 131072;
    float* PRD = ws + o; o += 1280;
    float* WEF = ws + o; o += 5120;
    float* BEF = ws + o; o += 1024;

    float* OUT0 = (float*)d_out;
    float* OUT1 = OUT0 + (size_t)B_ * TLEN_ * DI_;

    dim3 t256(256);

    init_kernel<<<dim3(512), t256, 0, stream>>>(HX1, HX2, PRD);
    pack_kernel<<<dim3(256), t256, 0, stream>>>(whh_d1, PKD1);
    pack_kernel<<<dim3(256), t256, 0, stream>>>(wih_d2, PKD2);
    weff_kernel<<<dim3(4), t256, 0, stream>>>(wih_d1, wdi, bdi, b_d1, WEF, BEF);

    // encoder: dynamic LDS = 3*2048*16 + 32*65*16 = 98304 + 33280 = 131584 B
    const unsigned encShm = 3 * 2048 * 16 + 32 * 65 * 16;
    hipFuncSetAttribute((const void*)enc_persist3,
                        hipFuncAttributeMaxDynamicSharedMemorySize, (int)encShm);
    {
        void* args[] = {
            (void*)&srcs, (void*)&wih_e1, (void*)&whh_e1, (void*)&wih_e2, (void*)&whh_e2,
            (void*)&b_e1, (void*)&b_e2, (void*)&HX1, (void*)&HX2,
            (void*)&C2g, (void*)&H2F, (void*)&ENCBF
        };
        hipLaunchCooperativeKernel((void*)enc_persist3, dim3(256), dim3(512),
                                   args, encShm, stream);
    }

    // decoder: dynamic LDS = 2*64*65*16 + 16*260*4 = 149760 B
    const unsigned decShm = 2 * 64 * 65 * 16 + 16 * 260 * 4;
    hipFuncSetAttribute((const void*)dec_persist2,
                        hipFuncAttributeMaxDynamicSharedMemorySize, (int)decShm);
    {
        void* args[] = {
            (void*)&WEF, (void*)&PKD1, (void*)&PKD2, (void*)&BEF, (void*)&b_d2,
            (void*)&H2F, (void*)&C2g, (void*)&H1D, (void*)&EN, (void*)&WSM,
            (void*)&PRD, (void*)&ENCBF,
            (void*)&ww, (void*)&bw, (void*)&wop, (void*)&bop,
            (void*)&OUT0, (void*)&OUT1
        };
        hipLaunchCooperativeKernel((void*)dec_persist2, dim3(256), t256, args, decShm, stream);
    }
}

// Round 7
// 24755.086 us; speedup vs baseline: 1.8342x; 1.3281x over previous
//
#include <hip/hip_runtime.h>
#include <hip/hip_bf16.h>

#define B_    256
#define S_    512
#define H_    256
#define TLEN_ 32
#define DI_   5
#define ENCSTRIDE 131072   // S_*H_

// ---------------------------------------------------------------------------
// init: zero h ping-pong buffers + barrier counters, set decoder inp0 = ones
// ---------------------------------------------------------------------------
__global__ __launch_bounds__(256) void init_kernel(float* HX1, float* HX2, float* PRD,
                                                   unsigned* BARS) {
    int i = blockIdx.x * 256 + threadIdx.x;      // grid 512 -> 131072
    HX1[i] = 0.f; HX2[i] = 0.f;
    if (i < B_ * DI_) PRD[i] = 1.0f;
    if (i < 2048) BARS[i] = 0u;
}

// ---------------------------------------------------------------------------
// pack a [1024][256] row-major weight into [k4][n] float4 layout (decoder)
// ---------------------------------------------------------------------------
__global__ __launch_bounds__(256) void pack_kernel(const float* __restrict__ m,
                                                   float4* __restrict__ out) {
    int idx = blockIdx.x * 256 + threadIdx.x;    // grid 256 -> 65536
    int k4 = idx >> 10, n = idx & 1023;
    out[idx] = ((const float4*)m)[n * 64 + k4];
}

// ---------------------------------------------------------------------------
// Weff[n][m] = sum_k wih_d1[n][k]*wdi[k][m]; beff[n] = b_d1[n] + wih_d1[n]·bdi
// ---------------------------------------------------------------------------
__global__ __launch_bounds__(256) void weff_kernel(const float* __restrict__ wih_d1,
                                                   const float* __restrict__ wdi,
                                                   const float* __restrict__ bdi,
                                                   const float* __restrict__ b_d1,
                                                   float* __restrict__ weff,
                                                   float* __restrict__ beff) {
    int n = blockIdx.x * 256 + threadIdx.x;      // grid 4 -> 1024
    float acc[DI_] = {0.f, 0.f, 0.f, 0.f, 0.f};
    float accb = 0.f;
    for (int k = 0; k < H_; k++) {
        float w = wih_d1[n * H_ + k];
        accb += w * bdi[k];
#pragma unroll
        for (int m = 0; m < DI_; m++) acc[m] += w * wdi[k * DI_ + m];
    }
#pragma unroll
    for (int m = 0; m < DI_; m++) weff[n * DI_ + m] = acc[m];
    beff[n] = b_d1[n] + accb;
}

// ---------------------------------------------------------------------------
__device__ __forceinline__ void dot4(const float4 xv, const float4 w0, const float4 w1,
                                     const float4 w2, const float4 w3,
                                     float& a0, float& a1, float& a2, float& a3) {
    a0 += xv.x * w0.x + xv.y * w0.y + xv.z * w0.z + xv.w * w0.w;
    a1 += xv.x * w1.x + xv.y * w1.y + xv.z * w1.z + xv.w * w1.w;
    a2 += xv.x * w2.x + xv.y * w2.y + xv.z * w2.z + xv.w * w2.w;
    a3 += xv.x * w3.x + xv.y * w3.y + xv.z * w3.z + xv.w * w3.w;
}

__device__ __forceinline__ void lstm_epilogue(float a0, float a1, float a2, float a3,
                                              float cold, float& cn, float& hn) {
    float ii = 1.f / (1.f + expf(-a0));
    float ff = 1.f / (1.f + expf(-a1));
    float gg = tanhf(a2);
    float oo = 1.f / (1.f + expf(-a3));
    cn = ff * cold + ii * gg;
    hn = oo * tanhf(cn);
}

// ---------------------------------------------------------------------------
// Monotonic-counter barrier, agent scope. target = members * phase.
// Counters MUST be on separate 256B-padded slots (BARS[g*64]).
// ---------------------------------------------------------------------------
__device__ __forceinline__ void bar_sync(unsigned* cnt, unsigned target) {
    __syncthreads();
    if (threadIdx.x == 0) {
        __threadfence();   // release: L2 writeback of this XCD's stores
        __hip_atomic_fetch_add(cnt, 1u, __ATOMIC_RELEASE, __HIP_MEMORY_SCOPE_AGENT);
        while (__hip_atomic_load(cnt, __ATOMIC_ACQUIRE, __HIP_MEMORY_SCOPE_AGENT) < target)
            __builtin_amdgcn_s_sleep(1);
        __threadfence();   // acquire: invalidate stale cached lines
    }
    __syncthreads();
}

// ---------------------------------------------------------------------------
// Persistent encoder v3 (R6 compute, group barriers). 256 blocks x 512 thr.
// Group g = bid>>5 (32 blocks) owns batch rows [g*32,+32) — groups never
// exchange data, so sync is per-group. Block col-tile j0 = (bid&31)*8.
// Threads 0..255 layer-1 step t; 256..511 layer-2 step t-1 (pipeline).
// Weight slices LDS-resident; h1 tile staged in LDS; h2 rows from L2.
// ---------------------------------------------------------------------------
extern __shared__ char dynlds[];
__global__ __launch_bounds__(512, 1) void enc_persist3(
    const float* __restrict__ srcs,
    const float* __restrict__ wih_e1, const float* __restrict__ whh_e1,
    const float* __restrict__ wih_e2, const float* __restrict__ whh_e2,
    const float* __restrict__ b_e1, const float* __restrict__ b_e2,
    float* __restrict__ HX1, float* __restrict__ HX2,
    float* __restrict__ C2g, float* __restrict__ H2F,
    __hip_bfloat16* __restrict__ encbf, unsigned* __restrict__ BARS)
{
    float4* wl1  = (float4*)dynlds;       // [64 k4][32] whh_e1 slice
    float4* wl2x = wl1 + 2048;            // wih_e2 slice
    float4* wl2h = wl2x + 2048;           // whh_e2 slice
    float4* sH1  = wl2h + 2048;           // [32 r][65] staged h1 tile

    const int tid = threadIdx.x, bid = blockIdx.x;
    const int b0 = (bid >> 5) * 32, j0 = (bid & 31) * 8;
    const int half = tid >> 8, t2 = tid & 255;
    const int bl = t2 >> 3, jl = t2 & 7;
    const int b = b0 + bl, j = j0 + jl;
    const int idx = b * H_ + j;
    unsigned* cnt = BARS + (bid >> 5) * 64;   // padded per-group counter

    // ---- load weight slices into LDS (once) ----
    for (int i = tid; i < 2048; i += 512) {
        int k4 = i >> 5, lgc = i & 31;           // lgc = g*8 + jj
        int g = lgc >> 3, jj = lgc & 7;
        int row = g * 256 + j0 + jj;
        wl1[i]  = ((const float4*)(whh_e1 + row * 256))[k4];
        wl2x[i] = ((const float4*)(wih_e2 + row * 256))[k4];
        wl2h[i] = ((const float4*)(whh_e2 + row * 256))[k4];
    }
    // ---- per-thread constants ----
    float bb[4], w1x[4][5];
    if (half == 0) {
#pragma unroll
        for (int g = 0; g < 4; g++) {
            bb[g] = b_e1[g * 256 + j];
#pragma unroll
            for (int k = 0; k < 5; k++) w1x[g][k] = wih_e1[(g * 256 + j) * 5 + k];
        }
    } else {
#pragma unroll
        for (int g = 0; g < 4; g++) bb[g] = b_e2[g * 256 + j];
    }
    float creg = 0.f;
    unsigned phase = 0;

    for (int t = 0; t <= S_; ++t) {
        // ---- stage h1_{t-1} (slot (t&1)^1), rows b0..b0+32, into sH1 ----
        {
            const float* hp = HX1 + (((t & 1) ^ 1) << 16);
            for (int i = tid; i < 2048; i += 512) {
                int r = i >> 6, c4 = i & 63;
                sH1[r * 65 + c4] = ((const float4*)(hp + (b0 + r) * 256))[c4];
            }
        }
        __syncthreads();

        if (half == 0) {
            // ================= layer 1, step t =================
            if (t < S_) {
                float a0 = bb[0], a1 = bb[1], a2 = bb[2], a3 = bb[3];
                const float* xp = srcs + ((long)b * S_ + t) * DI_;
#pragma unroll
                for (int k = 0; k < 5; k++) {
                    float xv = xp[k];
                    a0 += xv * w1x[0][k]; a1 += xv * w1x[1][k];
                    a2 += xv * w1x[2][k]; a3 += xv * w1x[3][k];
                }
#pragma unroll 4
                for (int k4 = 0; k4 < 64; k4++) {
                    float4 hv = sH1[bl * 65 + k4];
                    const float4* wp = wl1 + k4 * 32;
                    dot4(hv, wp[jl], wp[8 + jl], wp[16 + jl], wp[24 + jl],
                         a0, a1, a2, a3);
                }
                float cn, hn;
                lstm_epilogue(a0, a1, a2, a3, creg, cn, hn);
                creg = cn;
                HX1[((t & 1) << 16) + idx] = hn;
            }
        } else {
            // ================= layer 2, step u = t-1 =================
            if (t >= 1) {
                int u = t - 1;
                float a0 = bb[0], a1 = bb[1], a2 = bb[2], a3 = bb[3];
                // wih_e2 · h1_u  (sH1 holds h1_{t-1} = h1_u)
#pragma unroll 4
                for (int k4 = 0; k4 < 64; k4++) {
                    float4 hv = sH1[bl * 65 + k4];
                    const float4* wp = wl2x + k4 * 32;
                    dot4(hv, wp[jl], wp[8 + jl], wp[16 + jl], wp[24 + jl],
                         a0, a1, a2, a3);
                }
                // whh_e2 · h2_{u-1}  (global, slot (u-1)&1 = t&1)
                const float4* h2p = (const float4*)(HX2 + ((t & 1) << 16) + b * 256);
#pragma unroll 4
                for (int k4 = 0; k4 < 64; k4++) {
                    float4 hv = h2p[k4];
                    const float4* wp = wl2h + k4 * 32;
                    dot4(hv, wp[jl], wp[8 + jl], wp[16 + jl], wp[24 + jl],
                         a0, a1, a2, a3);
                }
                float cn, hn;
                lstm_epilogue(a0, a1, a2, a3, creg, cn, hn);
                creg = cn;
                HX2[((u & 1) << 16) + idx] = hn;
                encbf[(long)b * ENCSTRIDE + u * 256 + j] = __float2bfloat16(hn);
                if (u == S_ - 1) { C2g[idx] = creg; H2F[idx] = hn; }
            }
        }
        bar_sync(cnt, 32u * (++phase));
    }
}

// ---------------------------------------------------------------------------
// Persistent decoder (R6 compute, mixed-scope barriers). 256 blocks x 256 thr.
// b-group = bid>>4 (16 blocks). Per step: 3 group barriers (cell1->cell2,
// cell2->energies, decout->next cell1) + 2 full-grid barriers (energies->
// softmax->context, the batch/seq transposes).
// ---------------------------------------------------------------------------
__global__ __launch_bounds__(256, 1) void dec_persist2(
    const float* __restrict__ weff,
    const float4* __restrict__ PKD1, const float4* __restrict__ PKD2,
    const float* __restrict__ beff, const float* __restrict__ b_d2,
    float* __restrict__ H2F, const float* __restrict__ C2g,
    float* __restrict__ H1D, float* __restrict__ EN, float* __restrict__ WSM,
    float* __restrict__ PRD, const __hip_bfloat16* __restrict__ encbf,
    const float* __restrict__ ww, const float* __restrict__ bw,
    const float* __restrict__ wop, const float* __restrict__ bop,
    float* __restrict__ OUT0, float* __restrict__ OUT1,
    unsigned* __restrict__ BARS)
{
    float4* dwl1 = (float4*)dynlds;          // [64 k4][65 lgc] whh_d1 slice
    float4* dwl2 = dwl1 + 64 * 65;           // wih_d2 slice
    float*  sA   = (float*)(dwl2 + 64 * 65); // [16][260] stage / lh / lw / ctx
    __shared__ float sX[16][5];
    __shared__ float red[4];

    const int tid = threadIdx.x, bid = blockIdx.x;
    const int b0 = (bid >> 4) * 16, j0 = (bid & 15) * 16;
    const int bl = tid >> 4, jl = tid & 15;
    const int cb = b0 + bl, cj = j0 + jl;
    const int idx = cb * H_ + cj;
    unsigned* gcnt = BARS + 512 + (bid >> 4) * 64;  // 16 group counters
    unsigned* fcnt = BARS + 1536;                   // full-grid counter

    for (int i = tid; i < 4096; i += 256) {
        int k4 = i >> 6, lgc = i & 63;
        int gg = lgc >> 4, jj = lgc & 15;
        dwl1[k4 * 65 + lgc] = PKD1[(k4 << 10) + gg * 256 + j0 + jj];
        dwl2[k4 * 65 + lgc] = PKD2[(k4 << 10) + gg * 256 + j0 + jj];
    }

    float c2reg = C2g[idx];
    const float be0 = beff[cj], be1 = beff[256 + cj], be2v = beff[512 + cj], be3 = beff[768 + cj];
    const float bd0 = b_d2[cj], bd1 = b_d2[256 + cj], bd2v = b_d2[512 + cj], bd3 = b_d2[768 + cj];
    float wef[4][5];
#pragma unroll
    for (int g4 = 0; g4 < 4; g4++)
#pragma unroll
        for (int k = 0; k < 5; k++) wef[g4][k] = weff[(g4 * 256 + cj) * 5 + k];

    unsigned gph = 0, fph = 0;

    for (int t = 0; t < TLEN_; ++t) {
        // ---- cell1: x = PRD (K=5 via weff), h = H2F, c = c2reg -> H1D ----
        if (tid < 80) sX[tid / 5][tid % 5] = PRD[b0 * DI_ + tid];
        for (int i = tid; i < 1024; i += 256) {
            int r = i >> 6, c4 = i & 63;
            ((float4*)sA)[r * 65 + c4] = ((const float4*)(H2F + (b0 + r) * H_))[c4];
        }
        __syncthreads();
        {
            float a0 = be0, a1 = be1, a2 = be2v, a3 = be3;
#pragma unroll
            for (int k = 0; k < 5; k++) {
                float xv = sX[bl][k];
                a0 += xv * wef[0][k]; a1 += xv * wef[1][k];
                a2 += xv * wef[2][k]; a3 += xv * wef[3][k];
            }
#pragma unroll 4
            for (int k4 = 0; k4 < 64; k4++) {
                float4 xv = ((const float4*)sA)[bl * 65 + k4];
                const float4* wp = dwl1 + k4 * 65;
                dot4(xv, wp[jl], wp[16 + jl], wp[32 + jl], wp[48 + jl], a0, a1, a2, a3);
            }
            float cn, hn;
            lstm_epilogue(a0, a1, a2, a3, c2reg, cn, hn);
            H1D[idx] = hn;   // c1 discarded
        }
        bar_sync(gcnt, 16u * (++gph));

        // ---- cell2: x = H1D (K=256), h = c = 0 -> H2F, c2reg ----
        for (int i = tid; i < 1024; i += 256) {
            int r = i >> 6, c4 = i & 63;
            ((float4*)sA)[r * 65 + c4] = ((const float4*)(H1D + (b0 + r) * H_))[c4];
        }
        __syncthreads();
        {
            float a0 = bd0, a1 = bd1, a2 = bd2v, a3 = bd3;
#pragma unroll 4
            for (int k4 = 0; k4 < 64; k4++) {
                float4 xv = ((const float4*)sA)[bl * 65 + k4];
                const float4* wp = dwl2 + k4 * 65;
                dot4(xv, wp[jl], wp[16 + jl], wp[32 + jl], wp[48 + jl], a0, a1, a2, a3);
            }
            float cn, hn;
            lstm_epilogue(a0, a1, a2, a3, 0.f, cn, hn);
            c2reg = cn;
            H2F[idx] = hn;
        }
        bar_sync(gcnt, 16u * (++gph));

        // ---- energies: block b = bid (H2F row bid written by own group) ----
        {
            float* lh = sA;
            lh[tid] = H2F[bid * H_ + tid];
            __syncthreads();
            int w = tid >> 6, lane = tid & 63;
            float4 hv = ((const float4*)lh)[lane];
            for (int s = w; s < S_; s += 4) {
                ushort4 uv = ((const ushort4*)(encbf + (long)bid * ENCSTRIDE + s * H_))[lane];
                float p = hv.x * __uint_as_float((unsigned)uv.x << 16)
                        + hv.y * __uint_as_float((unsigned)uv.y << 16)
                        + hv.z * __uint_as_float((unsigned)uv.z << 16)
                        + hv.w * __uint_as_float((unsigned)uv.w << 16);
#pragma unroll
                for (int off = 32; off > 0; off >>= 1) p += __shfl_down(p, off);
                if (lane == 0) EN[s * B_ + bid] = p;
            }
            __syncthreads();
        }
        bar_sync(fcnt, 256u * (++fph));   // full grid: softmax needs all b

        // ---- softmax over b for s = bid, bid+256 ----
        {
#pragma unroll
            for (int rr = 0; rr < 2; rr++) {
                int s = bid + rr * 256;
                float v = EN[s * B_ + tid];
                float m = v;
#pragma unroll
                for (int off = 32; off > 0; off >>= 1) m = fmaxf(m, __shfl_down(m, off));
                if ((tid & 63) == 0) red[tid >> 6] = m;
                __syncthreads();
                m = fmaxf(fmaxf(red[0], red[1]), fmaxf(red[2], red[3]));
                __syncthreads();
                float e = expf(v - m);
                float p = e;
#pragma unroll
                for (int off = 32; off > 0; off >>= 1) p += __shfl_down(p, off);
                if ((tid & 63) == 0) red[tid >> 6] = p;
                __syncthreads();
                float sum = red[0] + red[1] + red[2] + red[3];
                WSM[s * B_ + tid] = e / sum;
                __syncthreads();
            }
        }
        bar_sync(fcnt, 256u * (++fph));   // full grid: context needs all s

        // ---- context + decout: block b = bid ----
        {
            float* lw = sA;           // 512 floats
            float* ctxb = sA + 1024;  // 256 floats
            lw[tid] = WSM[tid * B_ + bid];
            lw[256 + tid] = WSM[(256 + tid) * B_ + bid];
            __syncthreads();
            float acc = 0.f;
            const __hip_bfloat16* ep = encbf + (long)bid * ENCSTRIDE + tid;
#pragma unroll 8
            for (int s = 0; s < S_; s++) acc += lw[s] * __bfloat162float(ep[s * H_]);
            OUT1[(long)bid * (TLEN_ * H_) + t * H_ + tid] = acc;
            ctxb[tid] = acc;
            __syncthreads();
            if (tid < 64) {
                float a[DI_] = {0.f, 0.f, 0.f, 0.f, 0.f};
                for (int k = tid; k < 2 * H_; k += 64) {
                    float v = (k < H_) ? H2F[bid * H_ + k] : ctxb[k - H_];
#pragma unroll
                    for (int m = 0; m < DI_; m++) a[m] += v * ww[m * (2 * H_) + k];
                }
#pragma unroll
                for (int m = 0; m < DI_; m++)
                    for (int off = 32; off > 0; off >>= 1) a[m] += __shfl_down(a[m], off);
                if (tid == 0) {
                    float t5[DI_];
#pragma unroll
                    for (int m = 0; m < DI_; m++) t5[m] = tanhf(a[m] + bw[m]);
#pragma unroll
                    for (int m2 = 0; m2 < DI_; m2++) {
                        float o = bop[m2];
#pragma unroll
                        for (int m = 0; m < DI_; m++) o += t5[m] * wop[m2 * DI_ + m];
                        OUT0[(long)bid * (TLEN_ * DI_) + t * DI_ + m2] = o;
                        PRD[bid * DI_ + m2] = o;
                    }
                }
            }
        }
        bar_sync(gcnt, 16u * (++gph));    // group: next cell1 reads PRD rows of own group
    }
}

// ---------------------------------------------------------------------------
extern "C" void kernel_launch(void* const* d_in, const int* in_sizes, int n_in,
                              void* d_out, int out_size, void* d_ws, size_t ws_size,
                              hipStream_t stream) {
    const float* srcs   = (const float*)d_in[0];
    const float* wih_e1 = (const float*)d_in[1];
    const float* whh_e1 = (const float*)d_in[2];
    const float* b_e1   = (const float*)d_in[3];
    const float* wih_e2 = (const float*)d_in[4];
    const float* whh_e2 = (const float*)d_in[5];
    const float* b_e2   = (const float*)d_in[6];
    const float* wdi    = (const float*)d_in[7];
    const float* bdi    = (const float*)d_in[8];
    const float* wih_d1 = (const float*)d_in[9];
    const float* whh_d1 = (const float*)d_in[10];
    const float* b_d1   = (const float*)d_in[11];
    const float* wih_d2 = (const float*)d_in[12];
    const float* whh_d2 = (const float*)d_in[13];   // unused (h=0 in cell2)
    const float* b_d2   = (const float*)d_in[14];
    const float* ww     = (const float*)d_in[15];
    const float* bw     = (const float*)d_in[16];
    const float* wop    = (const float*)d_in[17];
    const float* bop    = (const float*)d_in[18];
    (void)whh_d2;

    float* ws = (float*)d_ws;
    __hip_bfloat16* ENCBF = (__hip_bfloat16*)d_ws;   // 33.5M bf16 = 16,777,216 float slots
    size_t o = 16777216;
    float4* PKD1 = (float4*)(ws + o); o += 262144;   // whh_d1 packed
    float4* PKD2 = (float4*)(ws + o); o += 262144;   // wih_d2 packed
    float* HX1 = ws + o; o += 131072;                // [2][65536]
    float* HX2 = ws + o; o += 131072;                // [2][65536]
    float* C2g = ws + o; o += 65536;
    float* H2F = ws + o; o += 65536;
    float* H1D = ws + o; o += 65536;
    float* EN  = ws + o; o += 131072;
    float* WSM = ws + o; o += 131072;
    float* PRD = ws + o; o += 1280;
    float* WEF = ws + o; o += 5120;
    float* BEF = ws + o; o += 1024;
    unsigned* BARS = (unsigned*)(ws + o); o += 2048; // padded barrier counters

    float* OUT0 = (float*)d_out;
    float* OUT1 = OUT0 + (size_t)B_ * TLEN_ * DI_;

    dim3 t256(256);

    init_kernel<<<dim3(512), t256, 0, stream>>>(HX1, HX2, PRD, BARS);
    pack_kernel<<<dim3(256), t256, 0, stream>>>(whh_d1, PKD1);
    pack_kernel<<<dim3(256), t256, 0, stream>>>(wih_d2, PKD2);
    weff_kernel<<<dim3(4), t256, 0, stream>>>(wih_d1, wdi, bdi, b_d1, WEF, BEF);

    // encoder: dynamic LDS = 3*2048*16 + 32*65*16 = 98304 + 33280 = 131584 B
    const unsigned encShm = 3 * 2048 * 16 + 32 * 65 * 16;
    hipFuncSetAttribute((const void*)enc_persist3,
                        hipFuncAttributeMaxDynamicSharedMemorySize, (int)encShm);
    {
        void* args[] = {
            (void*)&srcs, (void*)&wih_e1, (void*)&whh_e1, (void*)&wih_e2, (void*)&whh_e2,
            (void*)&b_e1, (void*)&b_e2, (void*)&HX1, (void*)&HX2,
            (void*)&C2g, (void*)&H2F, (void*)&ENCBF, (void*)&BARS
        };
        hipLaunchCooperativeKernel((void*)enc_persist3, dim3(256), dim3(512),
                                   args, encShm, stream);
    }

    // decoder: dynamic LDS = 2*64*65*16 + 16*260*4 = 149760 B
    const unsigned decShm = 2 * 64 * 65 * 16 + 16 * 260 * 4;
    hipFuncSetAttribute((const void*)dec_persist2,
                        hipFuncAttributeMaxDynamicSharedMemorySize, (int)decShm);
    {
        void* args[] = {
            (void*)&WEF, (void*)&PKD1, (void*)&PKD2, (void*)&BEF, (void*)&b_d2,
            (void*)&H2F, (void*)&C2g, (void*)&H1D, (void*)&EN, (void*)&WSM,
            (void*)&PRD, (void*)&ENCBF,
            (void*)&ww, (void*)&bw, (void*)&wop, (void*)&bop,
            (void*)&OUT0, (void*)&OUT1, (void*)&BARS
        };
        hipLaunchCooperativeKernel((void*)dec_persist2, dim3(256), t256, args, decShm, stream);
    }
}